// Round 5
// baseline (139.582 us; speedup 1.0000x reference)
//
#include <hip/hip_runtime.h>
#include <math.h>

#define NUM_CLASSES 80
#define C_CH (NUM_CLASSES + 1)
#define MAX_T 128   // dedup LDS capacity per wave (T=64 here)

__device__ __forceinline__ float softplusf(float x) {
    return fmaxf(x, 0.f) + log1pf(expf(-fabsf(x)));
}
__device__ __forceinline__ float sigmoidf_(float x) {
    return 1.f / (1.f + expf(-x));
}

// d_ws layout: 16 words zeroed by a 64-byte memset each call.
//  acc[0]=lb acc[1]=lo acc[2]=lc acc[3]=n
//  acc[4]=bg_plane_sp4 acc[5]=bg_plane_sp5
//  acc[6]=occ_sp4 acc[7]=occ_cnt4 acc[8]=occ_sp5 acc[9]=occ_cnt5
//  word 15 = done-counter (uint)
// Identity: bce_bg = plane_sum(softplus(ch0)) - occupied_sum; bg_cnt = B*HW - occ_cnt.

__global__ void __launch_bounds__(256) mono_kernel(
    const float* __restrict__ cls_p4, const float* __restrict__ reg_p4,
    const float* __restrict__ cls_p5, const float* __restrict__ reg_p5,
    const int* __restrict__ t4_cls, const float* __restrict__ t4_box, const float* __restrict__ t4_mask,
    const int* __restrict__ t5_cls, const float* __restrict__ t5_box, const float* __restrict__ t5_mask,
    float* __restrict__ acc, unsigned int* __restrict__ counter,
    int B, int T, int nT, int nblk_total, float* __restrict__ out)
{
    const int tid  = threadIdx.x;
    const int wave = tid >> 6;
    const int lane = tid & 63;
    const int blk  = (int)blockIdx.x;
    const int BT   = B * T;

    __shared__ float s4[4][4];

    if (blk < B) {
        // ---- role 1a: p4 channel-0 plane sum, one block per image ----
        const float* base = cls_p4 + (size_t)blk * (C_CH * 6400);
        const float4* v4 = (const float4*)base;
        float s = 0.f;
        #pragma unroll
        for (int k = 0; k < 6; k++) {
            float4 x = v4[k * 256 + tid];          // 6*1024 = 6144 floats
            s += softplusf(x.x) + softplusf(x.y) + softplusf(x.z) + softplusf(x.w);
        }
        s += softplusf(base[6144 + tid]);          // remaining 256
        for (int off = 32; off > 0; off >>= 1) s += __shfl_down(s, off, 64);
        if (lane == 0) s4[wave][0] = s;
        __syncthreads();
        if (tid == 0) atomicAdd(&acc[4], s4[0][0] + s4[1][0] + s4[2][0] + s4[3][0]);
    } else if (blk < 2 * B) {
        // ---- role 1b: p5 channel-0 plane sum, one block per image ----
        const int b = blk - B;
        const float* base = cls_p5 + (size_t)b * (C_CH * 1600);
        const float4* v4 = (const float4*)base;
        float4 x = v4[tid];                        // 1024 floats
        float s = softplusf(x.x) + softplusf(x.y) + softplusf(x.z) + softplusf(x.w);
        if (tid < 144) {                           // remaining 576
            float4 y = v4[256 + tid];
            s += softplusf(y.x) + softplusf(y.y) + softplusf(y.z) + softplusf(y.w);
        }
        for (int off = 32; off > 0; off >>= 1) s += __shfl_down(s, off, 64);
        if (lane == 0) s4[wave][0] = s;
        __syncthreads();
        if (tid == 0) atomicAdd(&acc[5], s4[0][0] + s4[1][0] + s4[2][0] + s4[3][0]);
    } else if (blk < 2 * B + nT) {
        // ---- role 2: per-target losses, 2 targets per wave, 8 per block ----
        const int pw = (blk - 2 * B) * 4 + wave;   // pair index
        float lbS = 0.f, loS = 0.f, lcS = 0.f, nS = 0.f;

        bool   ok[2];
        float  mask[2], tx[2], ty[2], tw[2], th[2];
        int    cid[2], gx[2], gy[2], HWv[2];
        const float* cvb[2]; const float* rgb[2];

        #pragma unroll
        for (int k = 0; k < 2; k++) {
            const int tg = pw * 2 + k;
            ok[k] = (tg < 2 * BT);
            cvb[k] = nullptr; rgb[k] = nullptr;
            if (ok[k]) {
                const int scale = (tg >= BT) ? 1 : 0;
                const int ti = scale ? tg - BT : tg;
                const int b = ti / T;
                const float* cls_p = scale ? cls_p5 : cls_p4;
                const float* reg_p = scale ? reg_p5 : reg_p4;
                const int*   tc    = scale ? t5_cls : t4_cls;
                const float* tb_   = scale ? t5_box : t4_box;
                const float* tm    = scale ? t5_mask : t4_mask;
                const int W = scale ? 40 : 80;
                const int HW = W * W;
                mask[k] = tm[ti];
                cid[k]  = tc[ti];
                tx[k] = tb_[ti * 4 + 0] * (float)W;
                ty[k] = tb_[ti * 4 + 1] * (float)W;
                tw[k] = tb_[ti * 4 + 2] * (float)W;
                th[k] = tb_[ti * 4 + 3] * (float)W;
                gx[k] = (int)fminf(fmaxf(tx[k], 0.f), (float)(W - 1));
                gy[k] = (int)fminf(fmaxf(ty[k], 0.f), (float)(W - 1));
                const int cell = gy[k] * W + gx[k];
                HWv[k] = HW;
                cvb[k] = cls_p + (size_t)b * C_CH * HW + cell;
                rgb[k] = reg_p + (size_t)(b * 4) * HW + cell;
            }
        }

        // issue ALL scattered loads for both targets before any use
        float x0[2], x1[2], rvq[2], objq[2];
        #pragma unroll
        for (int k = 0; k < 2; k++) {
            x0[k] = ok[k] ? cvb[k][(size_t)(lane + 1) * HWv[k]] : 0.f;
            x1[k] = (ok[k] && lane < NUM_CLASSES - 64) ? cvb[k][(size_t)(lane + 65) * HWv[k]] : 0.f;
            rvq[k]  = (ok[k] && lane < 4) ? rgb[k][(size_t)lane * HWv[k]] : 0.f;
            objq[k] = (ok[k] && lane == 0) ? cvb[k][0] : 0.f;
        }

        #pragma unroll
        for (int k = 0; k < 2; k++) {
            float fsum = 0.f;
            {   // class c = lane
                float x = x0[k];
                float tgt = (lane == cid[k]) ? 1.f : 0.f;
                float bce = softplusf(x) - x * tgt;
                float p = sigmoidf_(x);
                float pt = p * tgt + (1.f - p) * (1.f - tgt);
                float om = 1.f - pt;
                if (lane < NUM_CLASSES) fsum += 0.25f * om * om * bce;
            }
            if (lane < NUM_CLASSES - 64) {  // class c = lane + 64
                float x = x1[k];
                float tgt = (lane + 64 == cid[k]) ? 1.f : 0.f;
                float bce = softplusf(x) - x * tgt;
                float p = sigmoidf_(x);
                float pt = p * tgt + (1.f - p) * (1.f - tgt);
                float om = 1.f - pt;
                fsum += 0.25f * om * om * bce;
            }
            for (int off = 32; off > 0; off >>= 1) fsum += __shfl_down(fsum, off, 64);

            float rv0 = __shfl(rvq[k], 0, 64), rv1 = __shfl(rvq[k], 1, 64);
            float rv2 = __shfl(rvq[k], 2, 64), rv3 = __shfl(rvq[k], 3, 64);

            if (lane == 0 && ok[k]) {
                const float m = mask[k];
                lcS += (fsum * (1.f / (float)NUM_CLASSES)) * m;
                loS += softplusf(-objq[k]) * m;

                float dx = sigmoidf_(rv0), dy = sigmoidf_(rv1);
                float dw = expf(fminf(fmaxf(rv2, -4.f), 4.f));
                float dh = expf(fminf(fmaxf(rv3, -4.f), 4.f));
                float px = (float)gx[k] + dx, py = (float)gy[k] + dy;
                float d, a, s = 0.f;
                d = (px - dw * 0.5f) - (tx[k] - tw[k] * 0.5f); a = fabsf(d); s += (a < 1.f) ? 0.5f * d * d : a - 0.5f;
                d = (py - dh * 0.5f) - (ty[k] - th[k] * 0.5f); a = fabsf(d); s += (a < 1.f) ? 0.5f * d * d : a - 0.5f;
                d = (px + dw * 0.5f) - (tx[k] + tw[k] * 0.5f); a = fabsf(d); s += (a < 1.f) ? 0.5f * d * d : a - 0.5f;
                d = (py + dh * 0.5f) - (ty[k] + th[k] * 0.5f); a = fabsf(d); s += (a < 1.f) ? 0.5f * d * d : a - 0.5f;
                lbS += (s * 0.25f) * m;
                nS  += m;
            }
        }

        if (lane == 0) { s4[wave][0] = lbS; s4[wave][1] = loS; s4[wave][2] = lcS; s4[wave][3] = nS; }
        __syncthreads();
        if (tid < 4) {
            float v = s4[0][tid] + s4[1][tid] + s4[2][tid] + s4[3][tid];
            atomicAdd(&acc[tid], v);
        }
    } else {
        // ---- role 3: per-(image,scale) occupied-cell dedup + obj gather ----
        __shared__ unsigned int cells[4][MAX_T];
        const int p = (blk - 2 * B - nT) * 4 + wave;
        float osp = 0.f, ocnt = 0.f;
        const bool valid_pair = (p < 2 * B) && (T <= MAX_T);
        int scale = 0, b = 0, W = 80, HW = 6400;
        if (valid_pair) {
            scale = p / B; b = p - scale * B;
            const float* tb_ = scale ? t5_box : t4_box;
            const float* tm  = scale ? t5_mask : t4_mask;
            W = scale ? 40 : 80; HW = W * W;
            for (int i = lane; i < T; i += 64) {
                const int ti = b * T + i;
                unsigned int cellv = 0xFFFFFFFFu;
                if (tm[ti] > 0.f) {
                    const float txx = tb_[ti * 4 + 0] * (float)W;
                    const float tyy = tb_[ti * 4 + 1] * (float)W;
                    const int gxx = (int)fminf(fmaxf(txx, 0.f), (float)(W - 1));
                    const int gyy = (int)fminf(fmaxf(tyy, 0.f), (float)(W - 1));
                    cellv = (unsigned)(gyy * W + gxx);
                }
                cells[wave][i] = cellv;
            }
        }
        __syncthreads();
        if (valid_pair) {
            const float* cls_p = scale ? cls_p5 : cls_p4;
            for (int i = lane; i < T; i += 64) {
                unsigned int cv = cells[wave][i];
                if (cv != 0xFFFFFFFFu) {
                    bool first = true;
                    for (int j = 0; j < i; j++)
                        if (cells[wave][j] == cv) { first = false; break; }
                    if (first) {
                        osp  += softplusf(cls_p[(size_t)b * C_CH * HW + (int)cv]);
                        ocnt += 1.f;
                    }
                }
            }
        }
        for (int off = 32; off > 0; off >>= 1) {
            osp  += __shfl_down(osp,  off, 64);
            ocnt += __shfl_down(ocnt, off, 64);
        }
        if (lane == 0 && p < 2 * B) {
            atomicAdd(&acc[6 + 2 * scale], osp);
            atomicAdd(&acc[7 + 2 * scale], ocnt);
        }
        __syncthreads();   // keep barrier count uniform-ish within block (all same role)
    }

    // ---- completion: last block performs the scalar epilogue ----
    __syncthreads();
    if (tid == 0) {
        __threadfence();
        unsigned int old = atomicAdd(counter, 1u);
        if (old == (unsigned int)(nblk_total - 1)) {
            __threadfence();
            float t[10];
            #pragma unroll
            for (int k = 0; k < 10; k++) t[k] = atomicAdd(&acc[k], 0.f); // coherent read
            float lbt = t[0], lot = t[1], lct = t[2], nt = t[3];
            float bce_bg4 = t[4] - t[6];
            float bce_bg5 = t[5] - t[8];
            float cnt4 = (float)(B * 6400) - t[7];
            float cnt5 = (float)(B * 1600) - t[9];
            lot += 0.05f * ((cnt4 > 0.f) ? bce_bg4 / fmaxf(cnt4, 1.f) : 0.f);
            lot += 0.05f * ((cnt5 > 0.f) ? bce_bg5 / fmaxf(cnt5, 1.f) : 0.f);
            float nd = fmaxf(nt, 1.f);
            if (nt > 0.f) { lbt /= nd; lct /= nd; }
            lot /= fmaxf(nt, 1.f);
            out[0] = 2.0f * lbt + 1.0f * lot + 0.5f * lct;
        }
    }
}

extern "C" void kernel_launch(void* const* d_in, const int* in_sizes, int n_in,
                              void* d_out, int out_size, void* d_ws, size_t ws_size,
                              hipStream_t stream) {
    const float* cls_p4 = (const float*)d_in[0];
    const float* reg_p4 = (const float*)d_in[1];
    const float* cls_p5 = (const float*)d_in[2];
    const float* reg_p5 = (const float*)d_in[3];
    const int*   t4_cls = (const int*)d_in[4];
    const float* t4_box = (const float*)d_in[5];
    const float* t4_mask= (const float*)d_in[6];
    const int*   t5_cls = (const int*)d_in[7];
    const float* t5_box = (const float*)d_in[8];
    const float* t5_mask= (const float*)d_in[9];

    const int B = in_sizes[0] / (C_CH * 6400);   // cls_p4: B x 81 x 80 x 80
    const int T = in_sizes[4] / B;               // t4_cls: B x T
    const int BT = B * T;

    const int nT = (2 * BT + 7) / 8;             // 8 targets per block (2/wave x 4 waves)
    const int nd = (2 * B + 3) / 4;              // 4 (image,scale) pairs per block
    const int nblk_total = 2 * B + nT + nd;

    float* acc = (float*)d_ws;
    unsigned int* counter = (unsigned int*)d_ws + 15;

    hipMemsetAsync(d_ws, 0, 64, stream);

    mono_kernel<<<nblk_total, 256, 0, stream>>>(
        cls_p4, reg_p4, cls_p5, reg_p5,
        t4_cls, t4_box, t4_mask, t5_cls, t5_box, t5_mask,
        acc, counter, B, T, nT, nblk_total, (float*)d_out);
}